// Round 17
// baseline (411.446 us; speedup 1.0000x reference)
//
#include <hip/hip_runtime.h>
#include <hip/hip_cooperative_groups.h>

#define NPTS 8192
#define SPTS 2048
#define BATCH 4
#define CO 256
#define TOTAL_ROWS (BATCH * NPTS)  // 32768

namespace cg = cooperative_groups;

typedef __attribute__((ext_vector_type(4))) float f32x4;
typedef __attribute__((ext_vector_type(8))) short bf16x8s;
typedef __attribute__((ext_vector_type(4))) unsigned short u16x4;
typedef __attribute__((ext_vector_type(8))) unsigned short u16x8;
typedef __attribute__((ext_vector_type(4))) unsigned int u32x4;

__device__ __forceinline__ unsigned short f2bf(float f) {
  unsigned int u = __float_as_uint(f);
  u += 0x7FFFu + ((u >> 16) & 1u);   // RNE
  return (unsigned short)(u >> 16);
}
__device__ __forceinline__ float bf2f(unsigned short h) {
  return __uint_as_float(((unsigned int)h) << 16);
}
__device__ __forceinline__ unsigned int cvtpk(float lo, float hi) {
  unsigned int r;
  asm("v_cvt_pk_bf16_f32 %0, %1, %2" : "=v"(r) : "v"(lo), "v"(hi));
  return r;
}
__device__ __forceinline__ void gload_lds16(const void* g, void* l) {
  __builtin_amdgcn_global_load_lds((const __attribute__((address_space(1))) void*)g,
                                   (__attribute__((address_space(3))) void*)l, 16, 0, 0);
}

// packed layout for a [R][K] bf16 tensor (R%16==0, K%32==0), KT=K/32:
// elem(r,k) = ((r>>4)*KT + (k>>5))*512 + ((k>>3)&3)*128 + (r&15)*8 + (k&7)

// ---------------- merged prep: pack_w + 2 transposes + pack_xyz2 ----------------
__device__ __forceinline__ void transpose_body(
    const float* __restrict__ in, unsigned short* __restrict__ out,
    int C, int S, int KT, int packed, int bx, int by, int bz, int t,
    float (*LT)[65]) {
  const int s0 = bx * 64, c0 = by * 64;
  const float* inb = in + (size_t)bz * C * S;
  const int cr = t >> 4, sq = t & 15;
  #pragma unroll
  for (int it = 0; it < 4; ++it) {
    int cc = cr + it * 16;
    float4 v = *reinterpret_cast<const float4*>(inb + (size_t)(c0 + cc) * S + s0 + sq * 4);
    LT[sq * 4 + 0][cc] = v.x; LT[sq * 4 + 1][cc] = v.y;
    LT[sq * 4 + 2][cc] = v.z; LT[sq * 4 + 3][cc] = v.w;
  }
  __syncthreads();
  const int sr = t >> 2, cq = t & 3;
  u16x8 o0v, o1v;
  #pragma unroll
  for (int k = 0; k < 8; ++k) o0v[k] = f2bf(LT[sr][cq * 16 + k]);
  #pragma unroll
  for (int k = 0; k < 8; ++k) o1v[k] = f2bf(LT[sr][cq * 16 + 8 + k]);
  if (packed) {
    size_t rg = (size_t)bz * S + s0 + sr;
    int c = c0 + cq * 16;
    size_t ad = ((rg >> 4) * KT + (c >> 5)) * 512 + ((c >> 3) & 3) * 128 + (rg & 15) * 8;
    *reinterpret_cast<u16x8*>(out + ad) = o0v;
    *reinterpret_cast<u16x8*>(out + ad + 128) = o1v;
  } else {
    unsigned short* op = out + ((size_t)bz * S + s0 + sr) * 256 + c0 + cq * 16;
    *reinterpret_cast<u16x8*>(op) = o0v;
    *reinterpret_cast<u16x8*>(op + 8) = o1v;
  }
}

__global__ __launch_bounds__(256) void prep_all(
    const float* __restrict__ points2, unsigned short* __restrict__ p2t,
    const float* __restrict__ points1, unsigned short* __restrict__ X1,
    const float* __restrict__ w1, const float* __restrict__ w2,
    const float* __restrict__ w3, unsigned short* __restrict__ o1,
    unsigned short* __restrict__ o2, unsigned short* __restrict__ o3,
    const float* __restrict__ xyz2, float4* __restrict__ sptg) {
  __shared__ float LT[64][65];
  const int bid = blockIdx.x, t = threadIdx.x;
  if (bid < 512) {
    int x = bid & 31, y = (bid >> 5) & 3, z = bid >> 7;
    transpose_body(points2, p2t, 256, SPTS, 0, 0, x, y, z, t, LT);
  } else if (bid < 1536) {
    int b2 = bid - 512;
    int x = b2 & 127, y = (b2 >> 7) & 1, z = b2 >> 8;
    transpose_body(points1, X1, 128, NPTS, 12, 1, x, y, z, t, LT);
  } else if (bid < 1648) {
    int gid = (bid - 1536) * 256 + t;
    const float* src;
    unsigned short* dst;
    int K, cl;
    if (gid < 12288) { src = w1; dst = o1; K = 384; cl = gid; }
    else if (gid < 20480) { src = w2; dst = o2; K = 256; cl = gid - 12288; }
    else if (gid < 28672) { src = w3; dst = o3; K = 256; cl = gid - 20480; }
    else return;
    int cpo = K >> 3;
    int o = cl / cpo, k0 = (cl - o * cpo) * 8;
    float4 a = *reinterpret_cast<const float4*>(src + (size_t)o * K + k0);
    float4 b = *reinterpret_cast<const float4*>(src + (size_t)o * K + k0 + 4);
    u16x8 v;
    v[0] = f2bf(a.x); v[1] = f2bf(a.y); v[2] = f2bf(a.z); v[3] = f2bf(a.w);
    v[4] = f2bf(b.x); v[5] = f2bf(b.y); v[6] = f2bf(b.z); v[7] = f2bf(b.w);
    int KT = K >> 5;
    size_t ad = ((size_t)(o >> 4) * KT + (k0 >> 5)) * 512 + ((k0 >> 3) & 3) * 128 + (o & 15) * 8;
    *reinterpret_cast<u16x8*>(dst + ad) = v;
  } else {
    int gid = (bid - 1648) * 256 + t;
    const float* p = xyz2 + (size_t)gid * 3;
    float x = p[0], y = p[1], z = p[2];
    float b2 = __fadd_rn(__fadd_rn(__fmul_rn(x, x), __fmul_rn(y, y)), __fmul_rn(z, z));
    sptg[gid] = make_float4(x, y, z, b2);
  }
}

// ---------------- KNN (k=3) + fused IDW gather (frozen) ----------------
#define CSINS(q, dd, s)                                                    \
  do {                                                                     \
    float tt = dd; int ti = s;                                             \
    bool c0 = tt < d0[q];                                                  \
    float h = c0 ? d0[q] : tt; int hi_ = c0 ? i0[q] : ti;                  \
    d0[q] = c0 ? tt : d0[q];   i0[q] = c0 ? ti : i0[q];                    \
    tt = h; ti = hi_;                                                      \
    bool c1 = tt < d1[q];                                                  \
    h = c1 ? d1[q] : tt; hi_ = c1 ? i1[q] : ti;                            \
    d1[q] = c1 ? tt : d1[q];   i1[q] = c1 ? ti : i1[q];                    \
    tt = h; ti = hi_;                                                      \
    bool c2 = tt < d2[q];                                                  \
    d2[q] = c2 ? tt : d2[q];   i2[q] = c2 ? ti : i2[q];                    \
  } while (0)

#define INSK(x)                                                            \
  do {                                                                     \
    bool c0 = (x) < k0, c1 = (x) < k1, c2 = (x) < k2;                      \
    unsigned long long nk0 = c0 ? (x) : k0;                                \
    unsigned long long nk1 = c0 ? k0 : (c1 ? (x) : k1);                    \
    unsigned long long nk2 = c1 ? k1 : (c2 ? (x) : k2);                    \
    k0 = nk0; k1 = nk1; k2 = nk2;                                          \
  } while (0)

__device__ __forceinline__ unsigned long long packdi(float d, int i) {
  unsigned int b = __float_as_uint(d);
  unsigned int u = b ^ ((unsigned int)((int)b >> 31) | 0x80000000u);
  return ((unsigned long long)u << 32) | (unsigned int)i;
}
__device__ __forceinline__ float unpackd(unsigned long long k) {
  unsigned int u = (unsigned int)(k >> 32);
  unsigned int b = u ^ ((u & 0x80000000u) ? 0x80000000u : 0xFFFFFFFFu);
  return __uint_as_float(b);
}

__global__ __launch_bounds__(256) void knn_gather(
    const float* __restrict__ xyz1, const float4* __restrict__ sptg,
    const unsigned short* __restrict__ p2t, unsigned short* __restrict__ X1) {
  const int b = blockIdx.y, t = threadIdx.x;
  const int wave = t >> 6, lane = t & 63;
  const int nb = blockIdx.x * 16 + wave * 4;
  const float4* sp = sptg + (size_t)b * SPTS;

  float qx[4], qy[4], qz[4], a2[4];
  float d0[4], d1[4], d2[4];
  int i0[4], i1[4], i2[4];
  #pragma unroll
  for (int q = 0; q < 4; ++q) {
    const float* qp = xyz1 + ((size_t)b * NPTS + nb + q) * 3;
    qx[q] = qp[0]; qy[q] = qp[1]; qz[q] = qp[2];
    a2[q] = __fadd_rn(__fadd_rn(__fmul_rn(qx[q], qx[q]), __fmul_rn(qy[q], qy[q])),
                      __fmul_rn(qz[q], qz[q]));
    d0[q] = 1e30f; d1[q] = 1e30f; d2[q] = 1e30f;
    i0[q] = 0; i1[q] = 0; i2[q] = 0;
  }

  #pragma unroll 2
  for (int it = 0; it < SPTS / 128; ++it) {
    int sA = it * 128 + lane;
    int sB = sA + 64;
    float4 pA = sp[sA];
    float4 pB = sp[sB];
    #pragma unroll
    for (int q = 0; q < 4; ++q) {
      float dotA = __fadd_rn(__fadd_rn(__fmul_rn(qx[q], pA.x), __fmul_rn(qy[q], pA.y)),
                             __fmul_rn(qz[q], pA.z));
      float dA = __fsub_rn(__fadd_rn(a2[q], pA.w), __fmul_rn(2.0f, dotA));
      float dotB = __fadd_rn(__fadd_rn(__fmul_rn(qx[q], pB.x), __fmul_rn(qy[q], pB.y)),
                             __fmul_rn(qz[q], pB.z));
      float dB = __fsub_rn(__fadd_rn(a2[q], pB.w), __fmul_rn(2.0f, dotB));
      CSINS(q, dA, sA);
      CSINS(q, dB, sB);
    }
  }

  #pragma unroll
  for (int q = 0; q < 4; ++q) {
    unsigned long long k0 = packdi(d0[q], i0[q]);
    unsigned long long k1 = packdi(d1[q], i1[q]);
    unsigned long long k2 = packdi(d2[q], i2[q]);
    #pragma unroll
    for (int m = 1; m < 64; m <<= 1) {
      unsigned long long x0 = __shfl_xor(k0, m);
      unsigned long long x1 = __shfl_xor(k1, m);
      unsigned long long x2 = __shfl_xor(k2, m);
      INSK(x0); INSK(x1); INSK(x2);
    }
    int j0 = (int)(k0 & 0xFFFFFFFFu);
    int j1 = (int)(k1 & 0xFFFFFFFFu);
    int j2 = (int)(k2 & 0xFFFFFFFFu);
    float r0 = 1.0f / __fadd_rn(unpackd(k0), 1e-8f);
    float r1 = 1.0f / __fadd_rn(unpackd(k1), 1e-8f);
    float r2 = 1.0f / __fadd_rn(unpackd(k2), 1e-8f);
    float rs = __fadd_rn(__fadd_rn(r0, r1), r2);
    float w0 = r0 / rs, w1 = r1 / rs, w2 = r2 / rs;

    const unsigned short* rw0 = p2t + ((size_t)b * SPTS + j0) * 256 + lane * 4;
    const unsigned short* rw1 = p2t + ((size_t)b * SPTS + j1) * 256 + lane * 4;
    const unsigned short* rw2 = p2t + ((size_t)b * SPTS + j2) * 256 + lane * 4;
    u16x4 v0 = *reinterpret_cast<const u16x4*>(rw0);
    u16x4 v1 = *reinterpret_cast<const u16x4*>(rw1);
    u16x4 v2 = *reinterpret_cast<const u16x4*>(rw2);
    u16x4 o;
    #pragma unroll
    for (int e = 0; e < 4; ++e) {
      float f = w0 * bf2f(v0[e]) + w1 * bf2f(v1[e]) + w2 * bf2f(v2[e]);
      o[e] = f2bf(f);
    }
    size_t rg = (size_t)b * NPTS + nb + q;
    int ca = 128 + lane * 4;
    size_t ad = (rg >> 4) * 12 * 512 + (rg & 15) * 8 + (size_t)(ca >> 5) * 512 +
                ((ca >> 3) & 3) * 128 + (ca & 7);
    *reinterpret_cast<u16x4*>(X1 + ad) = o;
  }
}

// ---------------- R15 fallback GEMM v8 ----------------
template <int K, bool BNIN>
__global__ __launch_bounds__(256) void gemm_packed(
    const unsigned short* __restrict__ Wp, const unsigned short* __restrict__ Xp,
    const float* __restrict__ ssp, const float* __restrict__ bias,
    unsigned short* __restrict__ Z, float* __restrict__ part) {
  constexpr int KT = K / 32;
  __shared__ unsigned short Ws[4 * KT * 512];
  const int t = threadIdx.x, wave = t >> 6, lane = t & 63;
  const int lr = lane & 15, hi4 = lane >> 4;
  const int id = blockIdx.x;
  const int wg = (id & 7) * 64 + (id >> 3);
  const int br = wg >> 2;
  const int cb = wg & 3;

  const unsigned short* Xb = Xp + ((size_t)(br * 16 + wave * 4) * KT) * 512 + lane * 8;
  u16x8 xp[3][4];
  #pragma unroll
  for (int d = 0; d < 3; ++d)
    #pragma unroll
    for (int rr = 0; rr < 4; ++rr)
      xp[d][rr] = *reinterpret_cast<const u16x8*>(Xb + ((size_t)rr * KT + d) * 512);

  const unsigned short* Wsrc = Wp + (size_t)cb * 4 * KT * 512;
  constexpr int WCH = 4 * KT * 512 / 8;
  #pragma unroll
  for (int i = 0; i < WCH / 256; ++i)
    gload_lds16(Wsrc + (size_t)(t + i * 256) * 8, Ws + (t + i * 256) * 8);
  __syncthreads();

  f32x4 acc[4][4];
  #pragma unroll
  for (int rr = 0; rr < 4; ++rr)
    #pragma unroll
    for (int ot = 0; ot < 4; ++ot) acc[rr][ot] = (f32x4)0.f;

  #pragma unroll
  for (int kt = 0; kt < KT; ++kt) {
    const int slot = kt % 3;
    u16x8 xc[4];
    #pragma unroll
    for (int rr = 0; rr < 4; ++rr) xc[rr] = xp[slot][rr];
    if (kt + 3 < KT) {
      #pragma unroll
      for (int rr = 0; rr < 4; ++rr)
        xp[slot][rr] = *reinterpret_cast<const u16x8*>(Xb + ((size_t)rr * KT + kt + 3) * 512);
    }
    bf16x8s xf[4];
    if constexpr (BNIN) {
      const int cbase = kt * 32 + hi4 * 8;
      f32x4 s0 = *reinterpret_cast<const f32x4*>(ssp + cbase);
      f32x4 s1 = *reinterpret_cast<const f32x4*>(ssp + cbase + 4);
      f32x4 h0 = *reinterpret_cast<const f32x4*>(ssp + 256 + cbase);
      f32x4 h1 = *reinterpret_cast<const f32x4*>(ssp + 256 + cbase + 4);
      #pragma unroll
      for (int rr = 0; rr < 4; ++rr) {
        float y0 = fmaxf(s0[0] * bf2f(xc[rr][0]) + h0[0], 0.f);
        float y1 = fmaxf(s0[1] * bf2f(xc[rr][1]) + h0[1], 0.f);
        float y2 = fmaxf(s0[2] * bf2f(xc[rr][2]) + h0[2], 0.f);
        float y3 = fmaxf(s0[3] * bf2f(xc[rr][3]) + h0[3], 0.f);
        float y4 = fmaxf(s1[0] * bf2f(xc[rr][4]) + h1[0], 0.f);
        float y5 = fmaxf(s1[1] * bf2f(xc[rr][5]) + h1[1], 0.f);
        float y6 = fmaxf(s1[2] * bf2f(xc[rr][6]) + h1[2], 0.f);
        float y7 = fmaxf(s1[3] * bf2f(xc[rr][7]) + h1[3], 0.f);
        u32x4 xw = {cvtpk(y0, y1), cvtpk(y2, y3), cvtpk(y4, y5), cvtpk(y6, y7)};
        xf[rr] = *reinterpret_cast<bf16x8s*>(&xw);
      }
    } else {
      #pragma unroll
      for (int rr = 0; rr < 4; ++rr)
        xf[rr] = *reinterpret_cast<bf16x8s*>(&xc[rr]);
    }
    bf16x8s wf[4];
    #pragma unroll
    for (int ot = 0; ot < 4; ++ot)
      wf[ot] = *reinterpret_cast<const bf16x8s*>(Ws + (size_t)(ot * KT + kt) * 512 + lane * 8);
    #pragma unroll
    for (int rr = 0; rr < 4; ++rr)
      #pragma unroll
      for (int ot = 0; ot < 4; ++ot)
        acc[rr][ot] =
            __builtin_amdgcn_mfma_f32_16x16x32_bf16(wf[ot], xf[rr], acc[rr][ot], 0, 0, 0);
  }

  const size_t pbase = (size_t)(br * 4 + wave) * 512;
  #pragma unroll
  for (int ot = 0; ot < 4; ++ot) {
    const int o_c = cb * 64 + ot * 16 + hi4 * 4;
    f32x4 bv = *reinterpret_cast<const f32x4*>(bias + o_c);
    const int kto = o_c >> 5, hb = (o_c >> 3) & 3, e0 = o_c & 7;
    float sm[4] = {0.f, 0.f, 0.f, 0.f}, sq[4] = {0.f, 0.f, 0.f, 0.f};
    #pragma unroll
    for (int rr = 0; rr < 4; ++rr) {
      f32x4 v = acc[rr][ot] + bv;
      #pragma unroll
      for (int e = 0; e < 4; ++e) {
        sm[e] += v[e];
        sq[e] += v[e] * v[e];
      }
      unsigned int o01 = cvtpk(v[0], v[1]);
      unsigned int o23 = cvtpk(v[2], v[3]);
      size_t rtg = (size_t)br * 16 + wave * 4 + rr;
      size_t ad = (rtg * 8 + kto) * 512 + hb * 128 + lr * 8 + e0;
      *reinterpret_cast<uint2*>(Z + ad) = make_uint2(o01, o23);
    }
    #pragma unroll
    for (int m = 8; m >= 1; m >>= 1) {
      #pragma unroll
      for (int e = 0; e < 4; ++e) {
        sm[e] += __shfl_xor(sm[e], m);
        sq[e] += __shfl_xor(sq[e], m);
      }
    }
    if (lr == 0) {
      f32x4 vs = {sm[0], sm[1], sm[2], sm[3]};
      f32x4 vq = {sq[0], sq[1], sq[2], sq[3]};
      *reinterpret_cast<f32x4*>(part + pbase + o_c) = vs;
      *reinterpret_cast<f32x4*>(part + pbase + 256 + o_c) = vq;
    }
  }
}

// ---------------- reduce partials v2 (fallback) ----------------
__global__ __launch_bounds__(256) void reduce_stats(
    const float* __restrict__ part, const float* __restrict__ gamma,
    const float* __restrict__ beta, float* __restrict__ ss) {
  __shared__ float red[32][8];
  const int t = threadIdx.x;
  const int sg = t >> 3, co = t & 7;
  const int c = (co < 4) ? (blockIdx.x * 4 + co) : (256 + blockIdx.x * 4 + (co - 4));
  float sm = 0.f;
  #pragma unroll
  for (int k = 0; k < 16; ++k)
    sm += part[(size_t)(sg + 32 * k) * 512 + c];
  red[sg][co] = sm;
  __syncthreads();
  if (t < 8) {
    float s = 0.f;
    #pragma unroll
    for (int g = 0; g < 32; ++g) s += red[g][t];
    red[0][t] = s;
  }
  __syncthreads();
  if (t < 4) {
    int ch = blockIdx.x * 4 + t;
    const float inv = 1.0f / (float)TOTAL_ROWS;
    float mean = red[0][t] * inv;
    float var = red[0][t + 4] * inv - mean * mean;
    float sc = gamma[ch] * rsqrtf(var + 1e-5f);
    ss[ch] = sc;
    ss[256 + ch] = beta[ch] - mean * sc;
  }
}

// ---------------- fallback final: BN3 + residual(BN1 of Z1) + ReLU + transpose ----
__global__ __launch_bounds__(256) void bn_res_out(
    const unsigned short* __restrict__ Z, const unsigned short* __restrict__ Zres,
    const float* __restrict__ ss_res, const float* __restrict__ ss_out,
    float* __restrict__ out) {
  __shared__ float LT[64][65];
  const int b = blockIdx.z, n0 = blockIdx.x * 64, o0 = blockIdx.y * 64;
  const int t = threadIdx.x;
  #pragma unroll
  for (int i = 0; i < 2; ++i) {
    int cid = t + i * 256;
    int r = cid & 15, hi = (cid >> 4) & 3, ktl = (cid >> 6) & 1, rtl = cid >> 7;
    size_t rt = (size_t)b * (NPTS / 16) + (n0 >> 4) + rtl;
    int kt = (o0 >> 5) + ktl;
    size_t ad = (rt * 8 + kt) * 512 + hi * 128 + r * 8;
    u16x8 z = *reinterpret_cast<const u16x8*>(Z + ad);
    u16x8 x = *reinterpret_cast<const u16x8*>(Zres + ad);
    int ob = o0 + ktl * 32 + hi * 8;
    #pragma unroll
    for (int e = 0; e < 8; ++e) {
      int c = ob + e;
      float xv = fmaxf(ss_res[c] * bf2f(x[e]) + ss_res[256 + c], 0.f);
      LT[ktl * 32 + hi * 8 + e][rtl * 16 + r] =
          fmaxf(ss_out[c] * bf2f(z[e]) + ss_out[256 + c] + xv, 0.f);
    }
  }
  __syncthreads();
  const int orow = t >> 2, nq = t & 3;
  float* op = out + ((size_t)b * CO + o0 + orow) * NPTS + n0 + nq * 16;
  #pragma unroll
  for (int j = 0; j < 4; ++j) {
    float4 v = make_float4(LT[orow][nq * 16 + j * 4 + 0], LT[orow][nq * 16 + j * 4 + 1],
                           LT[orow][nq * 16 + j * 4 + 2], LT[orow][nq * 16 + j * 4 + 3]);
    *reinterpret_cast<float4*>(op + j * 4) = v;
  }
}

// ================= cooperative mega-kernel =================
template <int K>
__device__ __forceinline__ void mega_gemm(
    const unsigned short* __restrict__ Wp, const unsigned short* __restrict__ Xp,
    const float* __restrict__ bias, float* __restrict__ part,
    unsigned short* Ws, f32x4 (&acc)[4][4],
    int t, int wave, int lane, int lr, int hi4, int br, int cb) {
  constexpr int KT = K / 32;
  const unsigned short* Xb = Xp + ((size_t)(br * 16 + wave * 4) * KT) * 512 + lane * 8;
  u16x8 xpf[3][4];
  #pragma unroll
  for (int d = 0; d < 3; ++d)
    #pragma unroll
    for (int rr = 0; rr < 4; ++rr)
      xpf[d][rr] = *reinterpret_cast<const u16x8*>(Xb + ((size_t)rr * KT + d) * 512);

  const unsigned short* Wsrc = Wp + (size_t)cb * 4 * KT * 512;
  constexpr int WCH = 4 * KT * 512 / 8;
  #pragma unroll
  for (int i = 0; i < WCH / 256; ++i)
    gload_lds16(Wsrc + (size_t)(t + i * 256) * 8, Ws + (t + i * 256) * 8);
  __syncthreads();

  #pragma unroll
  for (int rr = 0; rr < 4; ++rr)
    #pragma unroll
    for (int ot = 0; ot < 4; ++ot) acc[rr][ot] = (f32x4)0.f;

  #pragma unroll
  for (int kt = 0; kt < KT; ++kt) {
    const int slot = kt % 3;
    u16x8 xc[4];
    #pragma unroll
    for (int rr = 0; rr < 4; ++rr) xc[rr] = xpf[slot][rr];
    if (kt + 3 < KT) {
      #pragma unroll
      for (int rr = 0; rr < 4; ++rr)
        xpf[slot][rr] = *reinterpret_cast<const u16x8*>(Xb + ((size_t)rr * KT + kt + 3) * 512);
    }
    bf16x8s wf[4];
    #pragma unroll
    for (int ot = 0; ot < 4; ++ot)
      wf[ot] = *reinterpret_cast<const bf16x8s*>(Ws + (size_t)(ot * KT + kt) * 512 + lane * 8);
    #pragma unroll
    for (int rr = 0; rr < 4; ++rr)
      #pragma unroll
      for (int ot = 0; ot < 4; ++ot)
        acc[rr][ot] = __builtin_amdgcn_mfma_f32_16x16x32_bf16(
            wf[ot], *reinterpret_cast<bf16x8s*>(&xc[rr]), acc[rr][ot], 0, 0, 0);
  }

  const size_t pbase = (size_t)(br * 4 + wave) * 512;
  #pragma unroll
  for (int ot = 0; ot < 4; ++ot) {
    const int o_c = cb * 64 + ot * 16 + hi4 * 4;
    f32x4 bv = *reinterpret_cast<const f32x4*>(bias + o_c);
    float sm[4] = {0.f, 0.f, 0.f, 0.f}, sq[4] = {0.f, 0.f, 0.f, 0.f};
    #pragma unroll
    for (int rr = 0; rr < 4; ++rr) {
      acc[rr][ot] += bv;
      #pragma unroll
      for (int e = 0; e < 4; ++e) {
        sm[e] += acc[rr][ot][e];
        sq[e] += acc[rr][ot][e] * acc[rr][ot][e];
      }
    }
    #pragma unroll
    for (int m = 8; m >= 1; m >>= 1) {
      #pragma unroll
      for (int e = 0; e < 4; ++e) {
        sm[e] += __shfl_xor(sm[e], m);
        sq[e] += __shfl_xor(sq[e], m);
      }
    }
    if (lr == 0) {
      f32x4 vs = {sm[0], sm[1], sm[2], sm[3]};
      f32x4 vq = {sq[0], sq[1], sq[2], sq[3]};
      *reinterpret_cast<f32x4*>(part + pbase + o_c) = vs;
      *reinterpret_cast<f32x4*>(part + pbase + 256 + o_c) = vq;
    }
  }
}

__device__ __forceinline__ void stats_ss(
    const float* __restrict__ part, const float* __restrict__ gamma,
    const float* __restrict__ beta, float* redf, int t, int cb) {
  const int cl = t & 63, qs = t >> 6;
  const int c = cb * 64 + cl;
  float sm = 0.f, sq = 0.f;
  #pragma unroll 4
  for (int i = 0; i < 128; ++i) {
    int s = qs * 128 + i;
    sm += part[(size_t)s * 512 + c];
    sq += part[(size_t)s * 512 + 256 + c];
  }
  redf[qs * 128 + cl * 2] = sm;
  redf[qs * 128 + cl * 2 + 1] = sq;
  __syncthreads();
  if (t < 64) {
    float s0 = redf[t * 2] + redf[128 + t * 2] + redf[256 + t * 2] + redf[384 + t * 2];
    float q0 = redf[t * 2 + 1] + redf[128 + t * 2 + 1] + redf[256 + t * 2 + 1] +
               redf[384 + t * 2 + 1];
    const float inv = 1.0f / (float)TOTAL_ROWS;
    float mean = s0 * inv;
    float var = q0 * inv - mean * mean;
    float sc = gamma[cb * 64 + t] * rsqrtf(var + 1e-5f);
    redf[512 + t * 2] = sc;
    redf[512 + t * 2 + 1] = beta[cb * 64 + t] - mean * sc;
  }
  __syncthreads();
}

__device__ __forceinline__ void epi_writeX(
    f32x4 (&acc)[4][4], const float* redf, unsigned short* __restrict__ Xdst,
    int lr, int hi4, int wave, int br, int cb) {
  #pragma unroll
  for (int ot = 0; ot < 4; ++ot) {
    const int o_c = cb * 64 + ot * 16 + hi4 * 4;
    const int ol = ot * 16 + hi4 * 4;
    float sc[4], sh[4];
    #pragma unroll
    for (int e = 0; e < 4; ++e) {
      sc[e] = redf[512 + (ol + e) * 2];
      sh[e] = redf[512 + (ol + e) * 2 + 1];
    }
    const int kto = o_c >> 5, hb = (o_c >> 3) & 3, e0 = o_c & 7;
    #pragma unroll
    for (int rr = 0; rr < 4; ++rr) {
      f32x4 v = acc[rr][ot];
      float y0 = fmaxf(sc[0] * v[0] + sh[0], 0.f);
      float y1 = fmaxf(sc[1] * v[1] + sh[1], 0.f);
      float y2 = fmaxf(sc[2] * v[2] + sh[2], 0.f);
      float y3 = fmaxf(sc[3] * v[3] + sh[3], 0.f);
      size_t rtg = (size_t)br * 16 + wave * 4 + rr;
      size_t ad = (rtg * 8 + kto) * 512 + hb * 128 + lr * 8 + e0;
      *reinterpret_cast<uint2*>(Xdst + ad) = make_uint2(cvtpk(y0, y1), cvtpk(y2, y3));
    }
  }
}

__global__ __launch_bounds__(256, 2) void mega(
    const unsigned short* __restrict__ Wb1, const unsigned short* __restrict__ Wb2,
    const unsigned short* __restrict__ Wb3, const unsigned short* __restrict__ X1,
    unsigned short* __restrict__ X2, unsigned short* __restrict__ X3,
    const float* __restrict__ b1, const float* __restrict__ b2,
    const float* __restrict__ b3, const float* __restrict__ g1,
    const float* __restrict__ be1, const float* __restrict__ g2,
    const float* __restrict__ be2, const float* __restrict__ g3,
    const float* __restrict__ be3, float* __restrict__ part,
    float* __restrict__ out) {
  __shared__ __align__(16) char smem[49152];
  unsigned short* Ws = reinterpret_cast<unsigned short*>(smem);
  float* redf = reinterpret_cast<float*>(smem);
  cg::grid_group grid = cg::this_grid();

  const int t = threadIdx.x, wave = t >> 6, lane = t & 63;
  const int lr = lane & 15, hi4 = lane >> 4;
  const int id = blockIdx.x;
  const int wg = (id & 7) * 64 + (id >> 3);
  const int br = wg >> 2, cb = wg & 3;

  f32x4 acc[4][4];

  mega_gemm<384>(Wb1, X1, b1, part, Ws, acc, t, wave, lane, lr, hi4, br, cb);
  grid.sync();
  stats_ss(part, g1, be1, redf, t, cb);
  epi_writeX(acc, redf, X2, lr, hi4, wave, br, cb);
  grid.sync();

  mega_gemm<256>(Wb2, X2, b2, part, Ws, acc, t, wave, lane, lr, hi4, br, cb);
  grid.sync();
  stats_ss(part, g2, be2, redf, t, cb);
  epi_writeX(acc, redf, X3, lr, hi4, wave, br, cb);
  grid.sync();

  mega_gemm<256>(Wb3, X3, b3, part, Ws, acc, t, wave, lane, lr, hi4, br, cb);
  grid.sync();
  stats_ss(part, g3, be3, redf, t, cb);
  #pragma unroll
  for (int ot = 0; ot < 4; ++ot) {
    const int ol = ot * 16 + hi4 * 4;
    const int o_c = cb * 64 + ol;
    float sc[4], sh[4];
    #pragma unroll
    for (int e = 0; e < 4; ++e) {
      sc[e] = redf[512 + (ol + e) * 2];
      sh[e] = redf[512 + (ol + e) * 2 + 1];
    }
    const int kto = o_c >> 5, hb = (o_c >> 3) & 3, e0 = o_c & 7;
    #pragma unroll
    for (int rr = 0; rr < 4; ++rr) {
      size_t rtg = (size_t)br * 16 + wave * 4 + rr;
      size_t ad = (rtg * 8 + kto) * 512 + hb * 128 + lr * 8 + e0;
      u16x4 xr = *reinterpret_cast<const u16x4*>(X2 + ad);
      #pragma unroll
      for (int e = 0; e < 4; ++e)
        acc[rr][ot][e] = fmaxf(sc[e] * acc[rr][ot][e] + sh[e] + bf2f(xr[e]), 0.f);
    }
  }
  __syncthreads();
  float* LT = redf;
  const int ob = br >> 5;
  const int nbase = (br & 31) * 256;
  #pragma unroll
  for (int c = 0; c < 2; ++c) {
    if ((wave >> 1) == c) {
      #pragma unroll
      for (int ot = 0; ot < 4; ++ot)
        #pragma unroll
        for (int rr = 0; rr < 4; ++rr)
          #pragma unroll
          for (int e = 0; e < 4; ++e)
            LT[(size_t)(ot * 16 + hi4 * 4 + e) * 136 + (wave & 1) * 64 + rr * 16 + lr] =
                acc[rr][ot][e];
    }
    __syncthreads();
    const int o_l = t >> 5, nq = t & 31;
    #pragma unroll
    for (int p = 0; p < 8; ++p) {
      f32x4 v = *reinterpret_cast<const f32x4*>(LT + (size_t)(p * 8 + o_l) * 136 + nq * 4);
      *reinterpret_cast<f32x4*>(out + ((size_t)(ob * 256 + cb * 64 + p * 8 + o_l)) * NPTS +
                                nbase + c * 128 + nq * 4) = v;
    }
    __syncthreads();
  }
}

extern "C" void kernel_launch(void* const* d_in, const int* in_sizes, int n_in,
                              void* d_out, int out_size, void* d_ws, size_t ws_size,
                              hipStream_t stream) {
  const float* xyz1    = (const float*)d_in[0];
  const float* xyz2    = (const float*)d_in[1];
  const float* points1 = (const float*)d_in[2];
  const float* points2 = (const float*)d_in[3];
  const float* fuse_w  = (const float*)d_in[4];
  const float* fuse_b  = (const float*)d_in[5];
  const float* fuse_g  = (const float*)d_in[6];
  const float* fuse_be = (const float*)d_in[7];
  const float* e1_w    = (const float*)d_in[8];
  const float* e1_b    = (const float*)d_in[9];
  const float* e1_g    = (const float*)d_in[10];
  const float* e1_be   = (const float*)d_in[11];
  const float* e2_w    = (const float*)d_in[12];
  const float* e2_b    = (const float*)d_in[13];
  const float* e2_g    = (const float*)d_in[14];
  const float* e2_be   = (const float*)d_in[15];
  float* out = (float*)d_out;

  char* w = (char*)d_ws;
  auto carve = [&](size_t bytes) {
    char* p = w;
    w += (bytes + 255) & ~(size_t)255;
    return p;
  };
  unsigned short* Wb1 = (unsigned short*)carve(98304 * 2);
  unsigned short* Wb2 = (unsigned short*)carve(65536 * 2);
  unsigned short* Wb3 = (unsigned short*)carve(65536 * 2);
  unsigned short* p2t = (unsigned short*)carve((size_t)BATCH * SPTS * 256 * 2);
  float4* sptg        = (float4*)carve((size_t)BATCH * SPTS * 16);
  unsigned short* X1  = (unsigned short*)carve((size_t)TOTAL_ROWS * 384 * 2);
  unsigned short* bufA= (unsigned short*)carve((size_t)TOTAL_ROWS * 256 * 2);  // X2 / Z1
  unsigned short* bufB= (unsigned short*)carve((size_t)TOTAL_ROWS * 256 * 2);  // X3 / Z2
  unsigned short* bufC= (unsigned short*)carve((size_t)TOTAL_ROWS * 256 * 2);  // Z3
  float* part         = (float*)carve((size_t)512 * 512 * 4);
  float* ss           = (float*)carve(3 * 512 * 4);

  prep_all<<<dim3(1680), 256, 0, stream>>>(points2, p2t, points1, X1,
                                           fuse_w, e1_w, e2_w, Wb1, Wb2, Wb3,
                                           xyz2, sptg);

  knn_gather<<<dim3(NPTS / 16, BATCH), 256, 0, stream>>>(xyz1, sptg, p2t, X1);

  // try cooperative mega-kernel; fall back to the proven R15 sequence on failure
  void* args[] = {
      (void*)&Wb1, (void*)&Wb2, (void*)&Wb3, (void*)&X1, (void*)&bufA, (void*)&bufB,
      (void*)&fuse_b, (void*)&e1_b, (void*)&e2_b,
      (void*)&fuse_g, (void*)&fuse_be, (void*)&e1_g, (void*)&e1_be,
      (void*)&e2_g, (void*)&e2_be, (void*)&part, (void*)&out};
  hipError_t err = hipLaunchCooperativeKernel(reinterpret_cast<void*>(mega), dim3(512),
                                              dim3(256), args, 0, stream);
  if (err != hipSuccess) {
    // R15 fallback: bufA=Z1, bufB=Z2, bufC=Z3
    gemm_packed<384, false><<<dim3(512), 256, 0, stream>>>(Wb1, X1, nullptr, fuse_b,
                                                           bufA, part);
    reduce_stats<<<dim3(64), 256, 0, stream>>>(part, fuse_g, fuse_be, ss);
    gemm_packed<256, true><<<dim3(512), 256, 0, stream>>>(Wb2, bufA, ss, e1_b, bufB, part);
    reduce_stats<<<dim3(64), 256, 0, stream>>>(part, e1_g, e1_be, ss + 512);
    gemm_packed<256, true><<<dim3(512), 256, 0, stream>>>(Wb3, bufB, ss + 512, e2_b,
                                                          bufC, part);
    reduce_stats<<<dim3(64), 256, 0, stream>>>(part, e2_g, e2_be, ss + 1024);
    bn_res_out<<<dim3(NPTS / 64, 4, BATCH), 256, 0, stream>>>(bufC, bufA, ss, ss + 1024,
                                                              out);
  }
}

// Round 18
// 145.253 us; speedup vs baseline: 2.8326x; 2.8326x over previous
//
#include <hip/hip_runtime.h>

#define NPTS 8192
#define SPTS 2048
#define BATCH 4
#define CO 256
#define TOTAL_ROWS (BATCH * NPTS)  // 32768

typedef __attribute__((ext_vector_type(4))) float f32x4;
typedef __attribute__((ext_vector_type(8))) short bf16x8s;
typedef __attribute__((ext_vector_type(4))) unsigned short u16x4;
typedef __attribute__((ext_vector_type(8))) unsigned short u16x8;
typedef __attribute__((ext_vector_type(4))) unsigned int u32x4;

__device__ __forceinline__ unsigned short f2bf(float f) {
  unsigned int u = __float_as_uint(f);
  u += 0x7FFFu + ((u >> 16) & 1u);   // RNE
  return (unsigned short)(u >> 16);
}
__device__ __forceinline__ float bf2f(unsigned short h) {
  return __uint_as_float(((unsigned int)h) << 16);
}
// HW packed f32->bf16 (RNE), 2 elements per instruction
__device__ __forceinline__ unsigned int cvtpk(float lo, float hi) {
  unsigned int r;
  asm("v_cvt_pk_bf16_f32 %0, %1, %2" : "=v"(r) : "v"(lo), "v"(hi));
  return r;
}
__device__ __forceinline__ void gload_lds16(const void* g, void* l) {
  __builtin_amdgcn_global_load_lds((const __attribute__((address_space(1))) void*)g,
                                   (__attribute__((address_space(3))) void*)l, 16, 0, 0);
}

// packed layout for a [R][K] bf16 tensor (R%16==0, K%32==0), KT=K/32:
// elem(r,k) = ((r>>4)*KT + (k>>5))*512 + ((k>>3)&3)*128 + (r&15)*8 + (k&7)

// ---------------- merged prep: pack_w + 2 transposes + pack_xyz2 ----------------
__device__ __forceinline__ void transpose_body(
    const float* __restrict__ in, unsigned short* __restrict__ out,
    int C, int S, int KT, int packed, int bx, int by, int bz, int t,
    float (*LT)[65]) {
  const int s0 = bx * 64, c0 = by * 64;
  const float* inb = in + (size_t)bz * C * S;
  const int cr = t >> 4, sq = t & 15;
  #pragma unroll
  for (int it = 0; it < 4; ++it) {
    int cc = cr + it * 16;
    float4 v = *reinterpret_cast<const float4*>(inb + (size_t)(c0 + cc) * S + s0 + sq * 4);
    LT[sq * 4 + 0][cc] = v.x; LT[sq * 4 + 1][cc] = v.y;
    LT[sq * 4 + 2][cc] = v.z; LT[sq * 4 + 3][cc] = v.w;
  }
  __syncthreads();
  const int sr = t >> 2, cq = t & 3;
  u16x8 o0v, o1v;
  #pragma unroll
  for (int k = 0; k < 8; ++k) o0v[k] = f2bf(LT[sr][cq * 16 + k]);
  #pragma unroll
  for (int k = 0; k < 8; ++k) o1v[k] = f2bf(LT[sr][cq * 16 + 8 + k]);
  if (packed) {
    size_t rg = (size_t)bz * S + s0 + sr;
    int c = c0 + cq * 16;
    size_t ad = ((rg >> 4) * KT + (c >> 5)) * 512 + ((c >> 3) & 3) * 128 + (rg & 15) * 8;
    *reinterpret_cast<u16x8*>(out + ad) = o0v;
    *reinterpret_cast<u16x8*>(out + ad + 128) = o1v;
  } else {
    unsigned short* op = out + ((size_t)bz * S + s0 + sr) * 256 + c0 + cq * 16;
    *reinterpret_cast<u16x8*>(op) = o0v;
    *reinterpret_cast<u16x8*>(op + 8) = o1v;
  }
}

__global__ __launch_bounds__(256) void prep_all(
    const float* __restrict__ points2, unsigned short* __restrict__ p2t,
    const float* __restrict__ points1, unsigned short* __restrict__ X1,
    const float* __restrict__ w1, const float* __restrict__ w2,
    const float* __restrict__ w3, unsigned short* __restrict__ o1,
    unsigned short* __restrict__ o2, unsigned short* __restrict__ o3,
    const float* __restrict__ xyz2, float4* __restrict__ sptg) {
  __shared__ float LT[64][65];
  const int bid = blockIdx.x, t = threadIdx.x;
  if (bid < 512) {
    int x = bid & 31, y = (bid >> 5) & 3, z = bid >> 7;
    transpose_body(points2, p2t, 256, SPTS, 0, 0, x, y, z, t, LT);
  } else if (bid < 1536) {
    int b2 = bid - 512;
    int x = b2 & 127, y = (b2 >> 7) & 1, z = b2 >> 8;
    transpose_body(points1, X1, 128, NPTS, 12, 1, x, y, z, t, LT);
  } else if (bid < 1648) {
    int gid = (bid - 1536) * 256 + t;
    const float* src;
    unsigned short* dst;
    int K, cl;
    if (gid < 12288) { src = w1; dst = o1; K = 384; cl = gid; }
    else if (gid < 20480) { src = w2; dst = o2; K = 256; cl = gid - 12288; }
    else if (gid < 28672) { src = w3; dst = o3; K = 256; cl = gid - 20480; }
    else return;
    int cpo = K >> 3;
    int o = cl / cpo, k0 = (cl - o * cpo) * 8;
    float4 a = *reinterpret_cast<const float4*>(src + (size_t)o * K + k0);
    float4 b = *reinterpret_cast<const float4*>(src + (size_t)o * K + k0 + 4);
    u16x8 v;
    v[0] = f2bf(a.x); v[1] = f2bf(a.y); v[2] = f2bf(a.z); v[3] = f2bf(a.w);
    v[4] = f2bf(b.x); v[5] = f2bf(b.y); v[6] = f2bf(b.z); v[7] = f2bf(b.w);
    int KT = K >> 5;
    size_t ad = ((size_t)(o >> 4) * KT + (k0 >> 5)) * 512 + ((k0 >> 3) & 3) * 128 + (o & 15) * 8;
    *reinterpret_cast<u16x8*>(dst + ad) = v;
  } else {
    int gid = (bid - 1648) * 256 + t;
    const float* p = xyz2 + (size_t)gid * 3;
    float x = p[0], y = p[1], z = p[2];
    float b2 = __fadd_rn(__fadd_rn(__fmul_rn(x, x), __fmul_rn(y, y)), __fmul_rn(z, z));
    sptg[gid] = make_float4(x, y, z, b2);
  }
}

// ---------------- KNN (k=3) + fused IDW gather ----------------
#define CSINS(q, dd, s)                                                    \
  do {                                                                     \
    float tt = dd; int ti = s;                                             \
    bool c0 = tt < d0[q];                                                  \
    float h = c0 ? d0[q] : tt; int hi_ = c0 ? i0[q] : ti;                  \
    d0[q] = c0 ? tt : d0[q];   i0[q] = c0 ? ti : i0[q];                    \
    tt = h; ti = hi_;                                                      \
    bool c1 = tt < d1[q];                                                  \
    h = c1 ? d1[q] : tt; hi_ = c1 ? i1[q] : ti;                            \
    d1[q] = c1 ? tt : d1[q];   i1[q] = c1 ? ti : i1[q];                    \
    tt = h; ti = hi_;                                                      \
    bool c2 = tt < d2[q];                                                  \
    d2[q] = c2 ? tt : d2[q];   i2[q] = c2 ? ti : i2[q];                    \
  } while (0)

#define INSK(x)                                                            \
  do {                                                                     \
    bool c0 = (x) < k0, c1 = (x) < k1, c2 = (x) < k2;                      \
    unsigned long long nk0 = c0 ? (x) : k0;                                \
    unsigned long long nk1 = c0 ? k0 : (c1 ? (x) : k1);                    \
    unsigned long long nk2 = c1 ? k1 : (c2 ? (x) : k2);                    \
    k0 = nk0; k1 = nk1; k2 = nk2;                                          \
  } while (0)

__device__ __forceinline__ unsigned long long packdi(float d, int i) {
  unsigned int b = __float_as_uint(d);
  unsigned int u = b ^ ((unsigned int)((int)b >> 31) | 0x80000000u);
  return ((unsigned long long)u << 32) | (unsigned int)i;
}
__device__ __forceinline__ float unpackd(unsigned long long k) {
  unsigned int u = (unsigned int)(k >> 32);
  unsigned int b = u ^ ((u & 0x80000000u) ? 0x80000000u : 0xFFFFFFFFu);
  return __uint_as_float(b);
}

__global__ __launch_bounds__(256) void knn_gather(
    const float* __restrict__ xyz1, const float4* __restrict__ sptg,
    const unsigned short* __restrict__ p2t, unsigned short* __restrict__ X1) {
  const int b = blockIdx.y, t = threadIdx.x;
  const int wave = t >> 6, lane = t & 63;
  const int nb = blockIdx.x * 16 + wave * 4;
  const float4* sp = sptg + (size_t)b * SPTS;

  float qx[4], qy[4], qz[4], a2[4];
  float d0[4], d1[4], d2[4];
  int i0[4], i1[4], i2[4];
  #pragma unroll
  for (int q = 0; q < 4; ++q) {
    const float* qp = xyz1 + ((size_t)b * NPTS + nb + q) * 3;
    qx[q] = qp[0]; qy[q] = qp[1]; qz[q] = qp[2];
    a2[q] = __fadd_rn(__fadd_rn(__fmul_rn(qx[q], qx[q]), __fmul_rn(qy[q], qy[q])),
                      __fmul_rn(qz[q], qz[q]));
    d0[q] = 1e30f; d1[q] = 1e30f; d2[q] = 1e30f;
    i0[q] = 0; i1[q] = 0; i2[q] = 0;
  }

  #pragma unroll 2
  for (int it = 0; it < SPTS / 128; ++it) {
    int sA = it * 128 + lane;
    int sB = sA + 64;
    float4 pA = sp[sA];
    float4 pB = sp[sB];
    #pragma unroll
    for (int q = 0; q < 4; ++q) {
      float dotA = __fadd_rn(__fadd_rn(__fmul_rn(qx[q], pA.x), __fmul_rn(qy[q], pA.y)),
                             __fmul_rn(qz[q], pA.z));
      float dA = __fsub_rn(__fadd_rn(a2[q], pA.w), __fmul_rn(2.0f, dotA));
      float dotB = __fadd_rn(__fadd_rn(__fmul_rn(qx[q], pB.x), __fmul_rn(qy[q], pB.y)),
                             __fmul_rn(qz[q], pB.z));
      float dB = __fsub_rn(__fadd_rn(a2[q], pB.w), __fmul_rn(2.0f, dotB));
      CSINS(q, dA, sA);
      CSINS(q, dB, sB);
    }
  }

  #pragma unroll
  for (int q = 0; q < 4; ++q) {
    unsigned long long k0 = packdi(d0[q], i0[q]);
    unsigned long long k1 = packdi(d1[q], i1[q]);
    unsigned long long k2 = packdi(d2[q], i2[q]);
    #pragma unroll
    for (int m = 1; m < 64; m <<= 1) {
      unsigned long long x0 = __shfl_xor(k0, m);
      unsigned long long x1 = __shfl_xor(k1, m);
      unsigned long long x2 = __shfl_xor(k2, m);
      INSK(x0); INSK(x1); INSK(x2);
    }
    int j0 = (int)(k0 & 0xFFFFFFFFu);
    int j1 = (int)(k1 & 0xFFFFFFFFu);
    int j2 = (int)(k2 & 0xFFFFFFFFu);
    float r0 = 1.0f / __fadd_rn(unpackd(k0), 1e-8f);
    float r1 = 1.0f / __fadd_rn(unpackd(k1), 1e-8f);
    float r2 = 1.0f / __fadd_rn(unpackd(k2), 1e-8f);
    float rs = __fadd_rn(__fadd_rn(r0, r1), r2);
    float w0 = r0 / rs, w1 = r1 / rs, w2 = r2 / rs;

    const unsigned short* rw0 = p2t + ((size_t)b * SPTS + j0) * 256 + lane * 4;
    const unsigned short* rw1 = p2t + ((size_t)b * SPTS + j1) * 256 + lane * 4;
    const unsigned short* rw2 = p2t + ((size_t)b * SPTS + j2) * 256 + lane * 4;
    u16x4 v0 = *reinterpret_cast<const u16x4*>(rw0);
    u16x4 v1 = *reinterpret_cast<const u16x4*>(rw1);
    u16x4 v2 = *reinterpret_cast<const u16x4*>(rw2);
    u16x4 o;
    #pragma unroll
    for (int e = 0; e < 4; ++e) {
      float f = w0 * bf2f(v0[e]) + w1 * bf2f(v1[e]) + w2 * bf2f(v2[e]);
      o[e] = f2bf(f);
    }
    size_t rg = (size_t)b * NPTS + nb + q;
    int ca = 128 + lane * 4;
    size_t ad = (rg >> 4) * 12 * 512 + (rg & 15) * 8 + (size_t)(ca >> 5) * 512 +
                ((ca >> 3) & 3) * 128 + (ca & 7);
    *reinterpret_cast<u16x4*>(X1 + ad) = o;
  }
}

// ---------------- packed bf16 MFMA GEMM v8 (frozen) ----------------
template <int K, bool BNIN>
__global__ __launch_bounds__(256) void gemm_packed(
    const unsigned short* __restrict__ Wp, const unsigned short* __restrict__ Xp,
    const float* __restrict__ ssp, const float* __restrict__ bias,
    unsigned short* __restrict__ Z, float* __restrict__ part) {
  constexpr int KT = K / 32;
  __shared__ unsigned short Ws[4 * KT * 512];
  const int t = threadIdx.x, wave = t >> 6, lane = t & 63;
  const int lr = lane & 15, hi4 = lane >> 4;
  const int id = blockIdx.x;
  const int wg = (id & 7) * 64 + (id >> 3);
  const int br = wg >> 2;
  const int cb = wg & 3;

  const unsigned short* Xb = Xp + ((size_t)(br * 16 + wave * 4) * KT) * 512 + lane * 8;
  u16x8 xp[3][4];
  #pragma unroll
  for (int d = 0; d < 3; ++d)
    #pragma unroll
    for (int rr = 0; rr < 4; ++rr)
      xp[d][rr] = *reinterpret_cast<const u16x8*>(Xb + ((size_t)rr * KT + d) * 512);

  const unsigned short* Wsrc = Wp + (size_t)cb * 4 * KT * 512;
  constexpr int WCH = 4 * KT * 512 / 8;
  #pragma unroll
  for (int i = 0; i < WCH / 256; ++i)
    gload_lds16(Wsrc + (size_t)(t + i * 256) * 8, Ws + (t + i * 256) * 8);
  __syncthreads();

  f32x4 acc[4][4];
  #pragma unroll
  for (int rr = 0; rr < 4; ++rr)
    #pragma unroll
    for (int ot = 0; ot < 4; ++ot) acc[rr][ot] = (f32x4)0.f;

  #pragma unroll
  for (int kt = 0; kt < KT; ++kt) {
    const int slot = kt % 3;
    u16x8 xc[4];
    #pragma unroll
    for (int rr = 0; rr < 4; ++rr) xc[rr] = xp[slot][rr];
    if (kt + 3 < KT) {
      #pragma unroll
      for (int rr = 0; rr < 4; ++rr)
        xp[slot][rr] = *reinterpret_cast<const u16x8*>(Xb + ((size_t)rr * KT + kt + 3) * 512);
    }
    bf16x8s xf[4];
    if constexpr (BNIN) {
      const int cbase = kt * 32 + hi4 * 8;
      f32x4 s0 = *reinterpret_cast<const f32x4*>(ssp + cbase);
      f32x4 s1 = *reinterpret_cast<const f32x4*>(ssp + cbase + 4);
      f32x4 h0 = *reinterpret_cast<const f32x4*>(ssp + 256 + cbase);
      f32x4 h1 = *reinterpret_cast<const f32x4*>(ssp + 256 + cbase + 4);
      #pragma unroll
      for (int rr = 0; rr < 4; ++rr) {
        float y0 = fmaxf(s0[0] * bf2f(xc[rr][0]) + h0[0], 0.f);
        float y1 = fmaxf(s0[1] * bf2f(xc[rr][1]) + h0[1], 0.f);
        float y2 = fmaxf(s0[2] * bf2f(xc[rr][2]) + h0[2], 0.f);
        float y3 = fmaxf(s0[3] * bf2f(xc[rr][3]) + h0[3], 0.f);
        float y4 = fmaxf(s1[0] * bf2f(xc[rr][4]) + h1[0], 0.f);
        float y5 = fmaxf(s1[1] * bf2f(xc[rr][5]) + h1[1], 0.f);
        float y6 = fmaxf(s1[2] * bf2f(xc[rr][6]) + h1[2], 0.f);
        float y7 = fmaxf(s1[3] * bf2f(xc[rr][7]) + h1[3], 0.f);
        u32x4 xw = {cvtpk(y0, y1), cvtpk(y2, y3), cvtpk(y4, y5), cvtpk(y6, y7)};
        xf[rr] = *reinterpret_cast<bf16x8s*>(&xw);
      }
    } else {
      #pragma unroll
      for (int rr = 0; rr < 4; ++rr)
        xf[rr] = *reinterpret_cast<bf16x8s*>(&xc[rr]);
    }
    bf16x8s wf[4];
    #pragma unroll
    for (int ot = 0; ot < 4; ++ot)
      wf[ot] = *reinterpret_cast<const bf16x8s*>(Ws + (size_t)(ot * KT + kt) * 512 + lane * 8);
    #pragma unroll
    for (int rr = 0; rr < 4; ++rr)
      #pragma unroll
      for (int ot = 0; ot < 4; ++ot)
        acc[rr][ot] =
            __builtin_amdgcn_mfma_f32_16x16x32_bf16(wf[ot], xf[rr], acc[rr][ot], 0, 0, 0);
  }

  const size_t pbase = (size_t)(br * 4 + wave) * 512;
  #pragma unroll
  for (int ot = 0; ot < 4; ++ot) {
    const int o_c = cb * 64 + ot * 16 + hi4 * 4;
    f32x4 bv = *reinterpret_cast<const f32x4*>(bias + o_c);
    const int kto = o_c >> 5, hb = (o_c >> 3) & 3, e0 = o_c & 7;
    float sm[4] = {0.f, 0.f, 0.f, 0.f}, sq[4] = {0.f, 0.f, 0.f, 0.f};
    #pragma unroll
    for (int rr = 0; rr < 4; ++rr) {
      f32x4 v = acc[rr][ot] + bv;
      #pragma unroll
      for (int e = 0; e < 4; ++e) {
        sm[e] += v[e];
        sq[e] += v[e] * v[e];
      }
      unsigned int o01 = cvtpk(v[0], v[1]);
      unsigned int o23 = cvtpk(v[2], v[3]);
      size_t rtg = (size_t)br * 16 + wave * 4 + rr;
      size_t ad = (rtg * 8 + kto) * 512 + hb * 128 + lr * 8 + e0;
      *reinterpret_cast<uint2*>(Z + ad) = make_uint2(o01, o23);
    }
    #pragma unroll
    for (int m = 8; m >= 1; m >>= 1) {
      #pragma unroll
      for (int e = 0; e < 4; ++e) {
        sm[e] += __shfl_xor(sm[e], m);
        sq[e] += __shfl_xor(sq[e], m);
      }
    }
    if (lr == 0) {
      f32x4 vs = {sm[0], sm[1], sm[2], sm[3]};
      f32x4 vq = {sq[0], sq[1], sq[2], sq[3]};
      *reinterpret_cast<f32x4*>(part + pbase + o_c) = vs;
      *reinterpret_cast<f32x4*>(part + pbase + 256 + o_c) = vq;
    }
  }
}

// ---------------- reduce partials v2: grid 64, short parallel chains ----------------
__global__ __launch_bounds__(256) void reduce_stats(
    const float* __restrict__ part, const float* __restrict__ gamma,
    const float* __restrict__ beta, float* __restrict__ ss) {
  __shared__ float red[32][8];
  const int t = threadIdx.x;
  const int sg = t >> 3, co = t & 7;
  const int c = (co < 4) ? (blockIdx.x * 4 + co) : (256 + blockIdx.x * 4 + (co - 4));
  float sm = 0.f;
  #pragma unroll
  for (int k = 0; k < 16; ++k)
    sm += part[(size_t)(sg + 32 * k) * 512 + c];
  red[sg][co] = sm;
  __syncthreads();
  if (t < 8) {
    float s = 0.f;
    #pragma unroll
    for (int g = 0; g < 32; ++g) s += red[g][t];
    red[0][t] = s;
  }
  __syncthreads();
  if (t < 4) {
    int ch = blockIdx.x * 4 + t;
    const float inv = 1.0f / (float)TOTAL_ROWS;
    float mean = red[0][t] * inv;
    float var = red[0][t + 4] * inv - mean * mean;
    float sc = gamma[ch] * rsqrtf(var + 1e-5f);
    ss[ch] = sc;
    ss[256 + ch] = beta[ch] - mean * sc;
  }
}

// ---------------- final: BN3 + residual(BN1 of Z1) + ReLU + transpose out ----------------
__global__ __launch_bounds__(256) void bn_res_out(
    const unsigned short* __restrict__ Z, const unsigned short* __restrict__ Zres,
    const float* __restrict__ ss_res, const float* __restrict__ ss_out,
    float* __restrict__ out) {
  __shared__ float LT[64][65];
  const int b = blockIdx.z, n0 = blockIdx.x * 64, o0 = blockIdx.y * 64;
  const int t = threadIdx.x;
  #pragma unroll
  for (int i = 0; i < 2; ++i) {
    int cid = t + i * 256;
    int r = cid & 15, hi = (cid >> 4) & 3, ktl = (cid >> 6) & 1, rtl = cid >> 7;
    size_t rt = (size_t)b * (NPTS / 16) + (n0 >> 4) + rtl;
    int kt = (o0 >> 5) + ktl;
    size_t ad = (rt * 8 + kt) * 512 + hi * 128 + r * 8;
    u16x8 z = *reinterpret_cast<const u16x8*>(Z + ad);
    u16x8 x = *reinterpret_cast<const u16x8*>(Zres + ad);
    int ob = o0 + ktl * 32 + hi * 8;
    #pragma unroll
    for (int e = 0; e < 8; ++e) {
      int c = ob + e;
      float xv = fmaxf(ss_res[c] * bf2f(x[e]) + ss_res[256 + c], 0.f);
      LT[ktl * 32 + hi * 8 + e][rtl * 16 + r] =
          fmaxf(ss_out[c] * bf2f(z[e]) + ss_out[256 + c] + xv, 0.f);
    }
  }
  __syncthreads();
  const int orow = t >> 2, nq = t & 3;
  float* op = out + ((size_t)b * CO + o0 + orow) * NPTS + n0 + nq * 16;
  #pragma unroll
  for (int j = 0; j < 4; ++j) {
    float4 v = make_float4(LT[orow][nq * 16 + j * 4 + 0], LT[orow][nq * 16 + j * 4 + 1],
                           LT[orow][nq * 16 + j * 4 + 2], LT[orow][nq * 16 + j * 4 + 3]);
    *reinterpret_cast<float4*>(op + j * 4) = v;
  }
}

extern "C" void kernel_launch(void* const* d_in, const int* in_sizes, int n_in,
                              void* d_out, int out_size, void* d_ws, size_t ws_size,
                              hipStream_t stream) {
  const float* xyz1    = (const float*)d_in[0];
  const float* xyz2    = (const float*)d_in[1];
  const float* points1 = (const float*)d_in[2];
  const float* points2 = (const float*)d_in[3];
  const float* fuse_w  = (const float*)d_in[4];
  const float* fuse_b  = (const float*)d_in[5];
  const float* fuse_g  = (const float*)d_in[6];
  const float* fuse_be = (const float*)d_in[7];
  const float* e1_w    = (const float*)d_in[8];
  const float* e1_b    = (const float*)d_in[9];
  const float* e1_g    = (const float*)d_in[10];
  const float* e1_be   = (const float*)d_in[11];
  const float* e2_w    = (const float*)d_in[12];
  const float* e2_b    = (const float*)d_in[13];
  const float* e2_g    = (const float*)d_in[14];
  const float* e2_be   = (const float*)d_in[15];
  float* out = (float*)d_out;

  char* w = (char*)d_ws;
  auto carve = [&](size_t bytes) {
    char* p = w;
    w += (bytes + 255) & ~(size_t)255;
    return p;
  };
  unsigned short* Wb1 = (unsigned short*)carve(98304 * 2);
  unsigned short* Wb2 = (unsigned short*)carve(65536 * 2);
  unsigned short* Wb3 = (unsigned short*)carve(65536 * 2);
  unsigned short* p2t = (unsigned short*)carve((size_t)BATCH * SPTS * 256 * 2);
  float4* sptg        = (float4*)carve((size_t)BATCH * SPTS * 16);
  unsigned short* X1  = (unsigned short*)carve((size_t)TOTAL_ROWS * 384 * 2);
  unsigned short* Z1  = (unsigned short*)carve((size_t)TOTAL_ROWS * 256 * 2);
  unsigned short* Z2  = (unsigned short*)carve((size_t)TOTAL_ROWS * 256 * 2);
  unsigned short* Z3  = (unsigned short*)carve((size_t)TOTAL_ROWS * 256 * 2);
  float* part         = (float*)carve((size_t)512 * 512 * 4);
  float* ss           = (float*)carve(3 * 512 * 4);

  // merged prep: transposes + weight pack + xyz2 pack (1680 blocks)
  prep_all<<<dim3(1680), 256, 0, stream>>>(points2, p2t, points1, X1,
                                           fuse_w, e1_w, e2_w, Wb1, Wb2, Wb3,
                                           xyz2, sptg);

  // KNN + fused IDW gather -> X1 packed (K=384, cols 128..383)
  knn_gather<<<dim3(NPTS / 16, BATCH), 256, 0, stream>>>(xyz1, sptg, p2t, X1);

  // stage 1: fuse (K=384), raw input
  gemm_packed<384, false><<<dim3(512), 256, 0, stream>>>(Wb1, X1, nullptr, fuse_b, Z1, part);
  reduce_stats<<<dim3(64), 256, 0, stream>>>(part, fuse_g, fuse_be, ss);

  // stage 2: net1 (K=256), BN1+ReLU fused into X path
  gemm_packed<256, true><<<dim3(512), 256, 0, stream>>>(Wb2, Z1, ss, e1_b, Z2, part);
  reduce_stats<<<dim3(64), 256, 0, stream>>>(part, e1_g, e1_be, ss + 512);

  // stage 3: net2 (K=256), BN2+ReLU fused into X path
  gemm_packed<256, true><<<dim3(512), 256, 0, stream>>>(Wb3, Z2, ss + 512, e2_b, Z3, part);
  reduce_stats<<<dim3(64), 256, 0, stream>>>(part, e2_g, e2_be, ss + 1024);

  // final: BN3(Z3) + residual BN1(Z1) + ReLU + transpose to out
  bn_res_out<<<dim3(NPTS / 64, 4, BATCH), 256, 0, stream>>>(Z3, Z1, ss, ss + 1024, out);
}